// Round 4
// baseline (691.554 us; speedup 1.0000x reference)
//
#include <hip/hip_runtime.h>
#include <hip/hip_bf16.h>

typedef __attribute__((ext_vector_type(8))) __bf16 bf16x8;
typedef __attribute__((ext_vector_type(4))) __bf16 bf16x4;
typedef __attribute__((ext_vector_type(4))) float f32x4;

#define M_TOT 8192
#define IN_DIM 4096
#define R_BLK 256
#define K_CNT 128
#define NT 64            // K-tiles of 64

__device__ __forceinline__ __bf16 f2bf(float f) { return (__bf16)f; }

#define BAR()    asm volatile("s_barrier" ::: "memory")
#define WAITL0() asm volatile("s_waitcnt lgkmcnt(0)" ::: "memory")
#define WAITV8() asm volatile("s_waitcnt vmcnt(8)" ::: "memory")
#define WAITV0() asm volatile("s_waitcnt vmcnt(0)" ::: "memory")

// ---------------- f32 -> bf16 bulk convert ----------------
__global__ void cvt_f32_bf16(const float* __restrict__ in, __bf16* __restrict__ out, int n8) {
  int i = blockIdx.x * blockDim.x + threadIdx.x;
  if (i >= n8) return;
  const f32x4* p = (const f32x4*)(in + (size_t)i * 8);
  f32x4 a = p[0], b = p[1];
  bf16x8 o;
  o[0] = f2bf(a[0]); o[1] = f2bf(a[1]); o[2] = f2bf(a[2]); o[3] = f2bf(a[3]);
  o[4] = f2bf(b[0]); o[5] = f2bf(b[1]); o[6] = f2bf(b[2]); o[7] = f2bf(b[3]);
  *(bf16x8*)(out + (size_t)i * 8) = o;
}

// ---------------- wbuild2: LDS-accumulated W^T, bf16 out ----------------
// grid = 256 r * 8 og ; each WG builds 2 rows of Wt (rows r*16+og*2 .. +1)
__global__ __launch_bounds__(256) void wbuild2(const float* __restrict__ v32,
                                               const int* __restrict__ cols,
                                               __bf16* __restrict__ Wbf) {
  __shared__ float lw[2 * IN_DIM];   // 32 KB
  __shared__ int lcol[K_CNT];
  int bg = blockIdx.x;
  int r = bg >> 3, og = bg & 7;
  int tid = threadIdx.x;
  if (tid < K_CNT) lcol[tid] = cols[r * K_CNT + tid];
#pragma unroll
  for (int z = 0; z < 8; ++z) ((f32x4*)lw)[z * 256 + tid] = (f32x4){0.f, 0.f, 0.f, 0.f};
  __syncthreads();
  const float* vbase = v32 + (size_t)r * K_CNT * 256 + og * 32;
  int kq = tid >> 3, l8 = tid & 7;            // 32 k per pass, 8 threads/k
  int o = l8 >> 2, ib = (l8 & 3) * 4;
#pragma unroll
  for (int pass = 0; pass < 4; ++pass) {
    int k = pass * 32 + kq;
    f32x4 v = *(const f32x4*)(vbase + (size_t)k * 256 + l8 * 4);
    int c = lcol[k];
    float* dst = &lw[o * IN_DIM + c * 16 + ib];
    atomicAdd(dst + 0, v[0]); atomicAdd(dst + 1, v[1]);
    atomicAdd(dst + 2, v[2]); atomicAdd(dst + 3, v[3]);
  }
  __syncthreads();
  __bf16* wb = Wbf + ((size_t)r * 16 + og * 2) * IN_DIM;
#pragma unroll
  for (int z = 0; z < 8; ++z) {
    int idx = z * 256 + tid;                  // f32x4 index over 2*4096/4
    f32x4 v = ((f32x4*)lw)[idx];
    bf16x4 pk = { f2bf(v[0]), f2bf(v[1]), f2bf(v[2]), f2bf(v[3]) };
    *(bf16x4*)(wb + (size_t)idx * 4) = pk;
  }
}

// ---------------- 256x256 8-phase GEMM: out = A[8192][4096] * Wt[4096][4096]^T ----------------
// 512 thr = 8 waves (2M x 4N); BK=64; 128 KB dyn LDS = 2 slots x (A 32K + B 32K).
__global__ __launch_bounds__(512, 2) void gemm8(const __bf16* __restrict__ A,
                                                const __bf16* __restrict__ Wt,
                                                float* __restrict__ out) {
  extern __shared__ char sm[];
  char* lA = sm;             // [2][256 rows][128 B]
  char* lB = sm + 65536;

  int b = blockIdx.x;
  int logical = (b & 7) * 64 + (b >> 3);      // 512 WGs, bijective XCD swizzle
  int mt = logical & 31, nt = logical >> 5;
  int m0 = mt * 256, n0 = nt * 256;

  int tid = threadIdx.x, lane = tid & 63, wave = tid >> 6;
  int l15 = lane & 15, j4 = lane >> 4;
  int wr = wave >> 2, wc = wave & 3;
  int rowc = lane >> 3, sblk = (lane & 7) ^ rowc;   // pre-swizzled global slot

  int swz = (l15 & 7) << 4;
  int cb0 = (j4 * 16) ^ swz;
  int cb1 = (64 + j4 * 16) ^ swz;
  int aOff = (wr * 128 + l15) * 128;
  int bOff = (wc * 64 + l15) * 128;

  f32x4 acc[8][4];
#pragma unroll
  for (int mi = 0; mi < 8; ++mi)
#pragma unroll
    for (int ni = 0; ni < 4; ++ni) acc[mi][ni] = (f32x4){0.f, 0.f, 0.f, 0.f};

#define STAGE_HALF(t, p, h) do { \
  int tk = (t) * 64; \
  _Pragma("unroll") \
  for (int j = 0; j < 2; ++j) { \
    int chunk = j * 8 + wave; \
    int row = (h) * 128 + chunk * 8 + rowc; \
    const __bf16* sa = A + (size_t)(m0 + row) * IN_DIM + tk + sblk * 8; \
    __builtin_amdgcn_global_load_lds((const __attribute__((address_space(1))) void*)sa, \
      (__attribute__((address_space(3))) void*)(lA + (p) * 32768 + (h) * 16384 + chunk * 1024), 16, 0, 0); \
    const __bf16* sb = Wt + (size_t)(n0 + row) * IN_DIM + tk + sblk * 8; \
    __builtin_amdgcn_global_load_lds((const __attribute__((address_space(1))) void*)sb, \
      (__attribute__((address_space(3))) void*)(lB + (p) * 32768 + (h) * 16384 + chunk * 1024), 16, 0, 0); \
  } \
} while (0)

#define TILE(p, DOST, tn, ...) { \
  char* pA = lA + (p) * 32768; char* pB = lB + (p) * 32768; \
  bf16x8 af0[8], af1[8], bf0[4], bf1[4]; \
  _Pragma("unroll") for (int mi = 0; mi < 8; ++mi) af0[mi] = *(const bf16x8*)(pA + aOff + mi * 2048 + cb0); \
  _Pragma("unroll") for (int ni = 0; ni < 4; ++ni) bf0[ni] = *(const bf16x8*)(pB + bOff + ni * 2048 + cb0); \
  __builtin_amdgcn_s_setprio(1); \
  _Pragma("unroll") for (int mi = 0; mi < 8; ++mi) \
  _Pragma("unroll") for (int ni = 0; ni < 2; ++ni) \
    acc[mi][ni] = __builtin_amdgcn_mfma_f32_16x16x32_bf16(af0[mi], bf0[ni], acc[mi][ni], 0, 0, 0); \
  __builtin_amdgcn_s_setprio(0); \
  BAR(); \
  _Pragma("unroll") for (int mi = 0; mi < 8; ++mi) af1[mi] = *(const bf16x8*)(pA + aOff + mi * 2048 + cb1); \
  _Pragma("unroll") for (int ni = 0; ni < 4; ++ni) bf1[ni] = *(const bf16x8*)(pB + bOff + ni * 2048 + cb1); \
  __builtin_amdgcn_s_setprio(1); \
  _Pragma("unroll") for (int mi = 0; mi < 8; ++mi) \
  _Pragma("unroll") for (int ni = 2; ni < 4; ++ni) \
    acc[mi][ni] = __builtin_amdgcn_mfma_f32_16x16x32_bf16(af0[mi], bf0[ni], acc[mi][ni], 0, 0, 0); \
  __builtin_amdgcn_s_setprio(0); \
  WAITL0(); BAR(); \
  if (DOST) STAGE_HALF(tn, p, 0); \
  __builtin_amdgcn_s_setprio(1); \
  _Pragma("unroll") for (int mi = 0; mi < 8; ++mi) \
  _Pragma("unroll") for (int ni = 0; ni < 2; ++ni) \
    acc[mi][ni] = __builtin_amdgcn_mfma_f32_16x16x32_bf16(af1[mi], bf1[ni], acc[mi][ni], 0, 0, 0); \
  __builtin_amdgcn_s_setprio(0); \
  BAR(); \
  if (DOST) STAGE_HALF(tn, p, 1); \
  __builtin_amdgcn_s_setprio(1); \
  _Pragma("unroll") for (int mi = 0; mi < 8; ++mi) \
  _Pragma("unroll") for (int ni = 2; ni < 4; ++ni) \
    acc[mi][ni] = __builtin_amdgcn_mfma_f32_16x16x32_bf16(af1[mi], bf1[ni], acc[mi][ni], 0, 0, 0); \
  __builtin_amdgcn_s_setprio(0); \
  __VA_ARGS__; BAR(); \
}

  // prologue: tiles 0,1 fully staged; wait tile 0 (tile 1's 8 loads stay in flight)
  STAGE_HALF(0, 0, 0); STAGE_HALF(0, 0, 1);
  STAGE_HALF(1, 1, 0); STAGE_HALF(1, 1, 1);
  WAITV8(); BAR();

  for (int tp = 0; tp < 31; ++tp) {
    int t0 = tp * 2;
    TILE(0, 1, t0 + 2, WAITV8());
    TILE(1, 1, t0 + 3, WAITV8());
  }
  TILE(0, 0, 0, WAITV0());   // tile 62
  TILE(1, 0, 0, );           // tile 63

  // epilogue: D layout col=lane&15, row=(lane>>4)*4+q
#pragma unroll
  for (int mi = 0; mi < 8; ++mi)
#pragma unroll
    for (int ni = 0; ni < 4; ++ni)
#pragma unroll
      for (int q = 0; q < 4; ++q) {
        int m = m0 + wr * 128 + mi * 16 + j4 * 4 + q;
        int n = n0 + wc * 64 + ni * 16 + l15;
        out[(size_t)m * IN_DIM + n] = acc[mi][ni][q];
      }
#undef TILE
#undef STAGE_HALF
}

// ---------------- fallback (direct f32 path, from round 1) ----------------
#define MT 256
#define NTHR 512
#define NWG ((M_TOT / MT) * R_BLK)

__launch_bounds__(NTHR, 4)
__global__ void bsmm_f32(const float* __restrict__ x32, const float* __restrict__ v32,
                         const int* __restrict__ cols, float* __restrict__ out) {
  __shared__ ushort lx[MT * 64];
  __shared__ ushort lv[16 * 64];
  __shared__ int lcol[K_CNT];
  int b = blockIdx.x;
  int logical = (b & 7) * (NWG >> 3) + (b >> 3);
  int mt = logical >> 8;
  int r  = logical & 255;
  int m0 = mt * MT;
  int tid = threadIdx.x;
  if (tid < K_CNT) lcol[tid] = cols[r * K_CNT + tid];
  int lane = tid & 63, wave = tid >> 6;
  int l15 = lane & 15, j4 = lane >> 4;
  f32x4 acc0 = {0.f, 0.f, 0.f, 0.f};
  f32x4 acc1 = {0.f, 0.f, 0.f, 0.f};
  for (int t = 0; t < K_CNT / 4; ++t) {
    __syncthreads();
#pragma unroll
    for (int s = 0; s < 4; ++s) {
      int ch = s * NTHR + tid;
      int row = ch >> 3, s8 = ch & 7;
      int cb = lcol[t * 4 + (s8 >> 1)];
      size_t goff = (size_t)(m0 + row) * IN_DIM + cb * 16 + (s8 & 1) * 8;
      const f32x4* p = (const f32x4*)(x32 + goff);
      f32x4 a = p[0], bq = p[1];
      bf16x8 val;
      val[0] = f2bf(a[0]);  val[1] = f2bf(a[1]);  val[2] = f2bf(a[2]);  val[3] = f2bf(a[3]);
      val[4] = f2bf(bq[0]); val[5] = f2bf(bq[1]); val[6] = f2bf(bq[2]); val[7] = f2bf(bq[3]);
      int byteo = row * 128 + ((s8 * 16) ^ ((row & 7) << 4));
      *(bf16x8*)((char*)lx + byteo) = val;
    }
    if (tid < 128) {
      int kb = tid >> 5, o = (tid >> 1) & 15, ih = tid & 1;
      size_t goff = ((size_t)r * K_CNT + t * 4 + kb) * 256 + o * 16 + ih * 8;
      const f32x4* p = (const f32x4*)(v32 + goff);
      f32x4 a = p[0], bq = p[1];
      bf16x8 val;
      val[0] = f2bf(a[0]);  val[1] = f2bf(a[1]);  val[2] = f2bf(a[2]);  val[3] = f2bf(a[3]);
      val[4] = f2bf(bq[0]); val[5] = f2bf(bq[1]); val[6] = f2bf(bq[2]); val[7] = f2bf(bq[3]);
      int byteo = o * 128 + (((kb * 2 + ih) * 16) ^ ((o & 7) << 4));
      *(bf16x8*)((char*)lv + byteo) = val;
    }
    __syncthreads();
#pragma unroll
    for (int ks = 0; ks < 2; ++ks) {
      int colb = ks * 64 + j4 * 16;
      bf16x8 bfrg = *(const bf16x8*)((char*)lv + l15 * 128 + (colb ^ ((l15 & 7) << 4)));
      int rowA0 = wave * 32 + l15;
      bf16x8 a0 = *(const bf16x8*)((char*)lx + rowA0 * 128 + (colb ^ ((rowA0 & 7) << 4)));
      int rowA1 = rowA0 + 16;
      bf16x8 a1 = *(const bf16x8*)((char*)lx + rowA1 * 128 + (colb ^ ((rowA1 & 7) << 4)));
      acc0 = __builtin_amdgcn_mfma_f32_16x16x32_bf16(a0, bfrg, acc0, 0, 0, 0);
      acc1 = __builtin_amdgcn_mfma_f32_16x16x32_bf16(a1, bfrg, acc1, 0, 0, 0);
    }
  }
#pragma unroll
  for (int q = 0; q < 4; ++q) {
    int row0 = m0 + wave * 32 + j4 * 4 + q;
    out[(size_t)row0 * 4096 + r * 16 + l15] = acc0[q];
    out[(size_t)(row0 + 16) * 4096 + r * 16 + l15] = acc1[q];
  }
}

extern "C" void kernel_launch(void* const* d_in, const int* in_sizes, int n_in,
                              void* d_out, int out_size, void* d_ws, size_t ws_size,
                              hipStream_t stream) {
  const float* x32 = (const float*)d_in[0];
  const float* v32 = (const float*)d_in[1];
  const int*   cols = (const int*)d_in[2];
  float* out = (float*)d_out;

  const size_t xel = (size_t)M_TOT * IN_DIM;   // 33.5M
  const size_t wel = (size_t)IN_DIM * IN_DIM;  // 16.8M
  const size_t need = xel * 2 + wel * 2;       // xbf + Wbf = 100.7 MB

  if (ws_size >= need) {
    __bf16* xbf = (__bf16*)d_ws;
    __bf16* Wbf = (__bf16*)((char*)d_ws + xel * 2);
    cvt_f32_bf16<<<(int)(xel / 8 / 256), 256, 0, stream>>>(x32, xbf, (int)(xel / 8));
    wbuild2<<<R_BLK * 8, 256, 0, stream>>>(v32, cols, Wbf);
    (void)hipFuncSetAttribute((const void*)gemm8,
                              hipFuncAttributeMaxDynamicSharedMemorySize, 131072);
    gemm8<<<512, 512, 131072, stream>>>(xbf, Wbf, out);
  } else {
    bsmm_f32<<<NWG, NTHR, 0, stream>>>(x32, v32, cols, out);
  }
}

// Round 6
// 598.113 us; speedup vs baseline: 1.1562x; 1.1562x over previous
//
#include <hip/hip_runtime.h>
#include <hip/hip_bf16.h>

typedef __attribute__((ext_vector_type(8))) __bf16 bf16x8;
typedef __attribute__((ext_vector_type(4))) __bf16 bf16x4;
typedef __attribute__((ext_vector_type(4))) float f32x4;

#define M_TOT 8192
#define IN_DIM 4096
#define R_BLK 256
#define K_CNT 128

__device__ __forceinline__ __bf16 f2bf(float f) { return (__bf16)f; }

#define BAR()    asm volatile("s_barrier" ::: "memory")
#define WAITL0() asm volatile("s_waitcnt lgkmcnt(0)" ::: "memory")
#define WAITV4() asm volatile("s_waitcnt vmcnt(4)" ::: "memory")
#define WAITV0() asm volatile("s_waitcnt vmcnt(0)" ::: "memory")
#define PRIO1()  __builtin_amdgcn_s_setprio(1)
#define PRIO0()  __builtin_amdgcn_s_setprio(0)

// ---------------- f32 -> bf16 bulk convert ----------------
__global__ void cvt_f32_bf16(const float* __restrict__ in, __bf16* __restrict__ out, int n8) {
  int i = blockIdx.x * blockDim.x + threadIdx.x;
  if (i >= n8) return;
  const f32x4* p = (const f32x4*)(in + (size_t)i * 8);
  f32x4 a = p[0], b = p[1];
  bf16x8 o;
  o[0] = f2bf(a[0]); o[1] = f2bf(a[1]); o[2] = f2bf(a[2]); o[3] = f2bf(a[3]);
  o[4] = f2bf(b[0]); o[5] = f2bf(b[1]); o[6] = f2bf(b[2]); o[7] = f2bf(b[3]);
  *(bf16x8*)(out + (size_t)i * 8) = o;
}

// ---------------- wbuild2: LDS-accumulated W^T, bf16 out ----------------
__global__ __launch_bounds__(256) void wbuild2(const float* __restrict__ v32,
                                               const int* __restrict__ cols,
                                               __bf16* __restrict__ Wbf) {
  __shared__ float lw[2 * IN_DIM];
  __shared__ int lcol[K_CNT];
  int bg = blockIdx.x;
  int r = bg >> 3, og = bg & 7;
  int tid = threadIdx.x;
  if (tid < K_CNT) lcol[tid] = cols[r * K_CNT + tid];
#pragma unroll
  for (int z = 0; z < 8; ++z) ((f32x4*)lw)[z * 256 + tid] = (f32x4){0.f, 0.f, 0.f, 0.f};
  __syncthreads();
  const float* vbase = v32 + (size_t)r * K_CNT * 256 + og * 32;
  int kq = tid >> 3, l8 = tid & 7;
  int o = l8 >> 2, ib = (l8 & 3) * 4;
#pragma unroll
  for (int pass = 0; pass < 4; ++pass) {
    int k = pass * 32 + kq;
    f32x4 v = *(const f32x4*)(vbase + (size_t)k * 256 + l8 * 4);
    int c = lcol[k];
    float* dst = &lw[o * IN_DIM + c * 16 + ib];
    atomicAdd(dst + 0, v[0]); atomicAdd(dst + 1, v[1]);
    atomicAdd(dst + 2, v[2]); atomicAdd(dst + 3, v[3]);
  }
  __syncthreads();
  __bf16* wb = Wbf + ((size_t)r * 16 + og * 2) * IN_DIM;
#pragma unroll
  for (int z = 0; z < 8; ++z) {
    int idx = z * 256 + tid;
    f32x4 v = ((f32x4*)lw)[idx];
    bf16x4 pk = { f2bf(v[0]), f2bf(v[1]), f2bf(v[2]), f2bf(v[3]) };
    *(bf16x4*)(wb + (size_t)idx * 4) = pk;
  }
}

// ---------------- 256x256 8-phase GEMM (faithful m201-style schedule) ----------------
// 512 thr = 8 waves (2M x 4N); BK=64; 128 KB dyn LDS = 2 slots x (A 32K + B 32K).
// Per phase: {ds_reads | stage 1 half-tile} BAR lgkm0 prio 16xMFMA prio BAR.
// vmcnt(4) at phases 4 and 8 only (2 half-tiles in flight).
__global__ __launch_bounds__(512, 2) void gemm8(const __bf16* __restrict__ A,
                                                const __bf16* __restrict__ Wt,
                                                float* __restrict__ out) {
  extern __shared__ char sm[];
  char* lA = sm;             // [2][256 rows][128 B]
  char* lB = sm + 65536;

  int b = blockIdx.x;
  int logical = (b & 7) * 64 + (b >> 3);      // 512 WGs, bijective XCD swizzle
  int mt = logical & 31, nt = logical >> 5;
  int m0 = mt * 256, n0 = nt * 256;

  int tid = threadIdx.x, lane = tid & 63, wave = tid >> 6;
  int l15 = lane & 15, j4 = lane >> 4;
  int wr = wave >> 2, wc = wave & 3;
  int rowc = lane >> 3, sblk = (lane & 7) ^ rowc;   // pre-swizzled global slot

  int swz = (l15 & 7) << 4;
  int aRow = (wr * 128 + l15) * 128;   // byte offset of mi=0 row
  int bRow = (wc * 64 + l15) * 128;

  f32x4 acc[8][4];
#pragma unroll
  for (int mi = 0; mi < 8; ++mi)
#pragma unroll
    for (int ni = 0; ni < 4; ++ni) acc[mi][ni] = (f32x4){0.f, 0.f, 0.f, 0.f};

  bf16x8 alo[8], ahi[8], bfr[4];   // bfr time-shared: lo (P1-P2), hi (P3-P4)

#define STAGE_A(t, h) do { int _p = (t) & 1; int _tk = (t) * 64; \
  _Pragma("unroll") for (int j = 0; j < 2; ++j) { \
    int chunk = j * 8 + wave; int row = (h) * 128 + chunk * 8 + rowc; \
    const __bf16* src = A + (size_t)(m0 + row) * IN_DIM + _tk + sblk * 8; \
    __builtin_amdgcn_global_load_lds((const __attribute__((address_space(1))) void*)src, \
      (__attribute__((address_space(3))) void*)(lA + _p * 32768 + (h) * 16384 + chunk * 1024), 16, 0, 0); \
  } } while (0)

#define STAGE_B(t, h) do { int _p = (t) & 1; int _tk = (t) * 64; \
  _Pragma("unroll") for (int j = 0; j < 2; ++j) { \
    int chunk = j * 8 + wave; int row = (h) * 128 + chunk * 8 + rowc; \
    const __bf16* src = Wt + (size_t)(n0 + row) * IN_DIM + _tk + sblk * 8; \
    __builtin_amdgcn_global_load_lds((const __attribute__((address_space(1))) void*)src, \
      (__attribute__((address_space(3))) void*)(lB + _p * 32768 + (h) * 16384 + chunk * 1024), 16, 0, 0); \
  } } while (0)

#define RD_ALO(p) { _Pragma("unroll") for (int mi = 0; mi < 4; ++mi) \
  _Pragma("unroll") for (int ks = 0; ks < 2; ++ks) \
    alo[mi * 2 + ks] = *(const bf16x8*)(lA + (p) * 32768 + aRow + mi * 2048 + ((ks * 64 + j4 * 16) ^ swz)); }
#define RD_AHI(p) { _Pragma("unroll") for (int mi = 0; mi < 4; ++mi) \
  _Pragma("unroll") for (int ks = 0; ks < 2; ++ks) \
    ahi[mi * 2 + ks] = *(const bf16x8*)(lA + (p) * 32768 + aRow + 8192 + mi * 2048 + ((ks * 64 + j4 * 16) ^ swz)); }
#define RD_BLO(p) { _Pragma("unroll") for (int ni = 0; ni < 2; ++ni) \
  _Pragma("unroll") for (int ks = 0; ks < 2; ++ks) \
    bfr[ni * 2 + ks] = *(const bf16x8*)(lB + (p) * 32768 + bRow + ni * 2048 + ((ks * 64 + j4 * 16) ^ swz)); }
#define RD_BHI(p) { _Pragma("unroll") for (int ni = 0; ni < 2; ++ni) \
  _Pragma("unroll") for (int ks = 0; ks < 2; ++ks) \
    bfr[ni * 2 + ks] = *(const bf16x8*)(lB + (p) * 32768 + bRow + 4096 + ni * 2048 + ((ks * 64 + j4 * 16) ^ swz)); }

#define MM(AF, M0, N0) { _Pragma("unroll") for (int mi = 0; mi < 4; ++mi) \
  _Pragma("unroll") for (int ni = 0; ni < 2; ++ni) \
  _Pragma("unroll") for (int ks = 0; ks < 2; ++ks) \
    acc[(M0) + mi][(N0) + ni] = __builtin_amdgcn_mfma_f32_16x16x32_bf16(AF[mi * 2 + ks], bfr[ni * 2 + ks], acc[(M0) + mi][(N0) + ni], 0, 0, 0); }

  // ---- prologue: tile0 fully + tile1 A-halves (12 loads); wait tile0 (4 outstanding)
  STAGE_A(0, 0); STAGE_A(0, 1); STAGE_B(0, 0); STAGE_B(0, 1);
  STAGE_A(1, 0); STAGE_A(1, 1);
  WAITV4(); BAR();

  for (int u = 0; u < 31; ++u) {
    int o = 2 * u + 1, e2 = 2 * u + 2, o2 = 2 * u + 3;
    // ---- tile e (slot 0)
    RD_ALO(0); RD_BLO(0); STAGE_B(o, 0);
    BAR(); WAITL0(); PRIO1(); MM(alo, 0, 0); PRIO0(); BAR();
    RD_AHI(0); STAGE_B(o, 1);
    BAR(); WAITL0(); PRIO1(); MM(ahi, 4, 0); PRIO0(); BAR();
    RD_BHI(0); STAGE_A(e2, 0);
    BAR(); WAITL0(); PRIO1(); MM(alo, 0, 2); PRIO0(); BAR();
    STAGE_A(e2, 1);
    PRIO1(); MM(ahi, 4, 2); PRIO0(); WAITV4(); BAR();
    // ---- tile o (slot 1)
    RD_ALO(1); RD_BLO(1); STAGE_B(e2, 0);
    BAR(); WAITL0(); PRIO1(); MM(alo, 0, 0); PRIO0(); BAR();
    RD_AHI(1); STAGE_B(e2, 1);
    BAR(); WAITL0(); PRIO1(); MM(ahi, 4, 0); PRIO0(); BAR();
    RD_BHI(1); STAGE_A(o2, 0);
    BAR(); WAITL0(); PRIO1(); MM(alo, 0, 2); PRIO0(); BAR();
    STAGE_A(o2, 1);
    PRIO1(); MM(ahi, 4, 2); PRIO0(); WAITV4(); BAR();
  }
  // ---- final iter (tiles 62 slot0, 63 slot1): stage only B(63), drain at P4
  RD_ALO(0); RD_BLO(0); STAGE_B(63, 0);
  BAR(); WAITL0(); PRIO1(); MM(alo, 0, 0); PRIO0(); BAR();
  RD_AHI(0); STAGE_B(63, 1);
  BAR(); WAITL0(); PRIO1(); MM(ahi, 4, 0); PRIO0(); BAR();
  RD_BHI(0);
  BAR(); WAITL0(); PRIO1(); MM(alo, 0, 2); PRIO0(); BAR();
  PRIO1(); MM(ahi, 4, 2); PRIO0(); WAITV0(); BAR();
  RD_ALO(1); RD_BLO(1);
  BAR(); WAITL0(); PRIO1(); MM(alo, 0, 0); PRIO0(); BAR();
  RD_AHI(1);
  BAR(); WAITL0(); PRIO1(); MM(ahi, 4, 0); PRIO0(); BAR();
  RD_BHI(1);
  BAR(); WAITL0(); PRIO1(); MM(alo, 0, 2); PRIO0(); BAR();
  PRIO1(); MM(ahi, 4, 2); PRIO0();

  // ---- epilogue: D layout col=lane&15, row=(lane>>4)*4+q
#pragma unroll
  for (int mi = 0; mi < 8; ++mi)
#pragma unroll
    for (int ni = 0; ni < 4; ++ni)
#pragma unroll
      for (int q = 0; q < 4; ++q) {
        int m = m0 + wr * 128 + mi * 16 + j4 * 4 + q;
        int n = n0 + wc * 64 + ni * 16 + l15;
        out[(size_t)m * IN_DIM + n] = acc[mi][ni][q];
      }
#undef MM
#undef RD_ALO
#undef RD_AHI
#undef RD_BLO
#undef RD_BHI
#undef STAGE_A
#undef STAGE_B
}

// ---------------- fallback (direct f32 path, from round 1) ----------------
#define MT 256
#define NTHR 512
#define NWG ((M_TOT / MT) * R_BLK)

__launch_bounds__(NTHR, 4)
__global__ void bsmm_f32(const float* __restrict__ x32, const float* __restrict__ v32,
                         const int* __restrict__ cols, float* __restrict__ out) {
  __shared__ ushort lx[MT * 64];
  __shared__ ushort lv[16 * 64];
  __shared__ int lcol[K_CNT];
  int b = blockIdx.x;
  int logical = (b & 7) * (NWG >> 3) + (b >> 3);
  int mt = logical >> 8;
  int r  = logical & 255;
  int m0 = mt * MT;
  int tid = threadIdx.x;
  if (tid < K_CNT) lcol[tid] = cols[r * K_CNT + tid];
  int lane = tid & 63, wave = tid >> 6;
  int l15 = lane & 15, j4 = lane >> 4;
  f32x4 acc0 = {0.f, 0.f, 0.f, 0.f};
  f32x4 acc1 = {0.f, 0.f, 0.f, 0.f};
  for (int t = 0; t < K_CNT / 4; ++t) {
    __syncthreads();
#pragma unroll
    for (int s = 0; s < 4; ++s) {
      int ch = s * NTHR + tid;
      int row = ch >> 3, s8 = ch & 7;
      int cb = lcol[t * 4 + (s8 >> 1)];
      size_t goff = (size_t)(m0 + row) * IN_DIM + cb * 16 + (s8 & 1) * 8;
      const f32x4* p = (const f32x4*)(x32 + goff);
      f32x4 a = p[0], bq = p[1];
      bf16x8 val;
      val[0] = f2bf(a[0]);  val[1] = f2bf(a[1]);  val[2] = f2bf(a[2]);  val[3] = f2bf(a[3]);
      val[4] = f2bf(bq[0]); val[5] = f2bf(bq[1]); val[6] = f2bf(bq[2]); val[7] = f2bf(bq[3]);
      int byteo = row * 128 + ((s8 * 16) ^ ((row & 7) << 4));
      *(bf16x8*)((char*)lx + byteo) = val;
    }
    if (tid < 128) {
      int kb = tid >> 5, o = (tid >> 1) & 15, ih = tid & 1;
      size_t goff = ((size_t)r * K_CNT + t * 4 + kb) * 256 + o * 16 + ih * 8;
      const f32x4* p = (const f32x4*)(v32 + goff);
      f32x4 a = p[0], bq = p[1];
      bf16x8 val;
      val[0] = f2bf(a[0]);  val[1] = f2bf(a[1]);  val[2] = f2bf(a[2]);  val[3] = f2bf(a[3]);
      val[4] = f2bf(bq[0]); val[5] = f2bf(bq[1]); val[6] = f2bf(bq[2]); val[7] = f2bf(bq[3]);
      int byteo = o * 128 + (((kb * 2 + ih) * 16) ^ ((o & 7) << 4));
      *(bf16x8*)((char*)lv + byteo) = val;
    }
    __syncthreads();
#pragma unroll
    for (int ks = 0; ks < 2; ++ks) {
      int colb = ks * 64 + j4 * 16;
      bf16x8 bfrg = *(const bf16x8*)((char*)lv + l15 * 128 + (colb ^ ((l15 & 7) << 4)));
      int rowA0 = wave * 32 + l15;
      bf16x8 a0 = *(const bf16x8*)((char*)lx + rowA0 * 128 + (colb ^ ((rowA0 & 7) << 4)));
      int rowA1 = rowA0 + 16;
      bf16x8 a1 = *(const bf16x8*)((char*)lx + rowA1 * 128 + (colb ^ ((rowA1 & 7) << 4)));
      acc0 = __builtin_amdgcn_mfma_f32_16x16x32_bf16(a0, bfrg, acc0, 0, 0, 0);
      acc1 = __builtin_amdgcn_mfma_f32_16x16x32_bf16(a1, bfrg, acc1, 0, 0, 0);
    }
  }
#pragma unroll
  for (int q = 0; q < 4; ++q) {
    int row0 = m0 + wave * 32 + j4 * 4 + q;
    out[(size_t)row0 * 4096 + r * 16 + l15] = acc0[q];
    out[(size_t)(row0 + 16) * 4096 + r * 16 + l15] = acc1[q];
  }
}

extern "C" void kernel_launch(void* const* d_in, const int* in_sizes, int n_in,
                              void* d_out, int out_size, void* d_ws, size_t ws_size,
                              hipStream_t stream) {
  const float* x32 = (const float*)d_in[0];
  const float* v32 = (const float*)d_in[1];
  const int*   cols = (const int*)d_in[2];
  float* out = (float*)d_out;

  const size_t xel = (size_t)M_TOT * IN_DIM;   // 33.5M
  const size_t wel = (size_t)IN_DIM * IN_DIM;  // 16.8M
  const size_t need = xel * 2 + wel * 2;       // xbf + Wbf = 100.7 MB

  if (ws_size >= need) {
    __bf16* xbf = (__bf16*)d_ws;
    __bf16* Wbf = (__bf16*)((char*)d_ws + xel * 2);
    cvt_f32_bf16<<<(int)(xel / 8 / 256), 256, 0, stream>>>(x32, xbf, (int)(xel / 8));
    wbuild2<<<R_BLK * 8, 256, 0, stream>>>(v32, cols, Wbf);
    (void)hipFuncSetAttribute((const void*)gemm8,
                              hipFuncAttributeMaxDynamicSharedMemorySize, 131072);
    gemm8<<<512, 512, 131072, stream>>>(xbf, Wbf, out);
  } else {
    bsmm_f32<<<NWG, NTHR, 0, stream>>>(x32, v32, cols, out);
  }
}

// Round 7
// 504.814 us; speedup vs baseline: 1.3699x; 1.1848x over previous
//
#include <hip/hip_runtime.h>
#include <hip/hip_bf16.h>

typedef __attribute__((ext_vector_type(8))) __bf16 bf16x8;
typedef __attribute__((ext_vector_type(4))) __bf16 bf16x4;
typedef __attribute__((ext_vector_type(4))) float f32x4;

#define M_TOT 8192
#define IN_DIM 4096
#define R_BLK 256
#define K_CNT 128

__device__ __forceinline__ __bf16 f2bf(float f) { return (__bf16)f; }

#define BAR()    asm volatile("s_barrier" ::: "memory")
#define WAITL0() asm volatile("s_waitcnt lgkmcnt(0)" ::: "memory")
#define WAITV8() asm volatile("s_waitcnt vmcnt(8)" ::: "memory")
#define WAITV4() asm volatile("s_waitcnt vmcnt(4)" ::: "memory")
#define WAITV0() asm volatile("s_waitcnt vmcnt(0)" ::: "memory")
#define PRIO1()  __builtin_amdgcn_s_setprio(1)
#define PRIO0()  __builtin_amdgcn_s_setprio(0)

// ---------------- f32 -> bf16 bulk convert ----------------
__global__ void cvt_f32_bf16(const float* __restrict__ in, __bf16* __restrict__ out, int n8) {
  int i = blockIdx.x * blockDim.x + threadIdx.x;
  if (i >= n8) return;
  const f32x4* p = (const f32x4*)(in + (size_t)i * 8);
  f32x4 a = p[0], b = p[1];
  bf16x8 o;
  o[0] = f2bf(a[0]); o[1] = f2bf(a[1]); o[2] = f2bf(a[2]); o[3] = f2bf(a[3]);
  o[4] = f2bf(b[0]); o[5] = f2bf(b[1]); o[6] = f2bf(b[2]); o[7] = f2bf(b[3]);
  *(bf16x8*)(out + (size_t)i * 8) = o;
}

// ---------------- wbuild2: LDS-accumulated W^T, bf16 out ----------------
__global__ __launch_bounds__(256) void wbuild2(const float* __restrict__ v32,
                                               const int* __restrict__ cols,
                                               __bf16* __restrict__ Wbf) {
  __shared__ float lw[2 * IN_DIM];
  __shared__ int lcol[K_CNT];
  int bg = blockIdx.x;
  int r = bg >> 3, og = bg & 7;
  int tid = threadIdx.x;
  if (tid < K_CNT) lcol[tid] = cols[r * K_CNT + tid];
#pragma unroll
  for (int z = 0; z < 8; ++z) ((f32x4*)lw)[z * 256 + tid] = (f32x4){0.f, 0.f, 0.f, 0.f};
  __syncthreads();
  const float* vbase = v32 + (size_t)r * K_CNT * 256 + og * 32;
  int kq = tid >> 3, l8 = tid & 7;
  int o = l8 >> 2, ib = (l8 & 3) * 4;
#pragma unroll
  for (int pass = 0; pass < 4; ++pass) {
    int k = pass * 32 + kq;
    f32x4 v = *(const f32x4*)(vbase + (size_t)k * 256 + l8 * 4);
    int c = lcol[k];
    float* dst = &lw[o * IN_DIM + c * 16 + ib];
    atomicAdd(dst + 0, v[0]); atomicAdd(dst + 1, v[1]);
    atomicAdd(dst + 2, v[2]); atomicAdd(dst + 3, v[3]);
  }
  __syncthreads();
  __bf16* wb = Wbf + ((size_t)r * 16 + og * 2) * IN_DIM;
#pragma unroll
  for (int z = 0; z < 8; ++z) {
    int idx = z * 256 + tid;
    f32x4 v = ((f32x4*)lw)[idx];
    bf16x4 pk = { f2bf(v[0]), f2bf(v[1]), f2bf(v[2]), f2bf(v[3]) };
    *(bf16x4*)(wb + (size_t)idx * 4) = pk;
  }
}

// ---------------- 256x256 GEMM, BK=32, 4-slot ring, 3-tile prefetch depth --------
// 512 thr = 8 waves (2M x 4N). LDS = 4 slots x (A 16K + B 16K) = 128 KB.
// Per tile: 2 phases x {ds_reads | stage half of tile t+3; BAR; lgkm0; 16 MFMA; BAR}
// Tile-end vmcnt(8): tile t+1 landed; 8 loads (t+2,t+3) stay in flight.
__global__ __launch_bounds__(512, 2) void gemm32(const __bf16* __restrict__ A,
                                                 const __bf16* __restrict__ Wt,
                                                 float* __restrict__ out) {
  extern __shared__ char sm[];
  char* lA = sm;              // [4][256 rows][64 B]
  char* lB = sm + 65536;

  int b = blockIdx.x;
  int logical = (b & 7) * 64 + (b >> 3);      // 512 WGs, bijective XCD swizzle
  int mt = logical & 31, nt = logical >> 5;
  int m0 = mt * 256, n0 = nt * 256;

  int tid = threadIdx.x, lane = tid & 63, wave = tid >> 6;
  int l15 = lane & 15, j4 = lane >> 4;
  int wr = wave >> 2, wc = wave & 3;
  int sblk2 = (lane & 3) ^ ((lane >> 3) & 3);   // pre-swizzled global 16B slot (involution)

  // read-side swizzled byte offset within a 64-B row (lane-constant)
  int cboff = (j4 * 16) ^ (((l15 >> 1) & 3) << 4);
  int aRow = (wr * 128 + l15) * 64;
  int bRow = (wc * 64 + l15) * 64;

  f32x4 acc[8][4];
#pragma unroll
  for (int mi = 0; mi < 8; ++mi)
#pragma unroll
    for (int ni = 0; ni < 4; ++ni) acc[mi][ni] = (f32x4){0.f, 0.f, 0.f, 0.f};

  bf16x8 a[8], b01[2], b23[2];

#define STAGE32_A(ts) do { int _sl = (int)(ts) & 3; int _tk = (int)(ts) * 32; \
  _Pragma("unroll") for (int j = 0; j < 2; ++j) { \
    int chunk = j * 8 + wave; int row = chunk * 16 + (lane >> 2); \
    const __bf16* src = A + (size_t)(m0 + row) * IN_DIM + _tk + sblk2 * 8; \
    __builtin_amdgcn_global_load_lds((const __attribute__((address_space(1))) void*)src, \
      (__attribute__((address_space(3))) void*)(lA + _sl * 16384 + chunk * 1024), 16, 0, 0); \
  } } while (0)

#define STAGE32_B(ts) do { int _sl = (int)(ts) & 3; int _tk = (int)(ts) * 32; \
  _Pragma("unroll") for (int j = 0; j < 2; ++j) { \
    int chunk = j * 8 + wave; int row = chunk * 16 + (lane >> 2); \
    const __bf16* src = Wt + (size_t)(n0 + row) * IN_DIM + _tk + sblk2 * 8; \
    __builtin_amdgcn_global_load_lds((const __attribute__((address_space(1))) void*)src, \
      (__attribute__((address_space(3))) void*)(lB + _sl * 16384 + chunk * 1024), 16, 0, 0); \
  } } while (0)

#define RD_A(p)  { _Pragma("unroll") for (int mi = 0; mi < 8; ++mi) \
    a[mi] = *(const bf16x8*)(lA + (p) * 16384 + aRow + mi * 1024 + cboff); }
#define RD_B01(p) { _Pragma("unroll") for (int ni = 0; ni < 2; ++ni) \
    b01[ni] = *(const bf16x8*)(lB + (p) * 16384 + bRow + ni * 1024 + cboff); }
#define RD_B23(p) { _Pragma("unroll") for (int ni = 0; ni < 2; ++ni) \
    b23[ni] = *(const bf16x8*)(lB + (p) * 16384 + bRow + (2 + ni) * 1024 + cboff); }

#define MM01() { _Pragma("unroll") for (int mi = 0; mi < 8; ++mi) \
  _Pragma("unroll") for (int ni = 0; ni < 2; ++ni) \
    acc[mi][ni] = __builtin_amdgcn_mfma_f32_16x16x32_bf16(a[mi], b01[ni], acc[mi][ni], 0, 0, 0); }
#define MM23() { _Pragma("unroll") for (int mi = 0; mi < 8; ++mi) \
  _Pragma("unroll") for (int ni = 0; ni < 2; ++ni) \
    acc[mi][2 + ni] = __builtin_amdgcn_mfma_f32_16x16x32_bf16(a[mi], b23[ni], acc[mi][2 + ni], 0, 0, 0); }

#define TILE32(p, DOST, ts, ...) { \
  RD_A(p); RD_B01(p); if (DOST) STAGE32_A(ts); \
  BAR(); WAITL0(); PRIO1(); MM01(); PRIO0(); BAR(); \
  RD_B23(p); if (DOST) STAGE32_B(ts); \
  BAR(); WAITL0(); PRIO1(); MM23(); PRIO0(); __VA_ARGS__; BAR(); \
}

  // ---- prologue: stage tiles 0,1,2 (12 loads); wait tile 0 (8 stay in flight)
  STAGE32_A(0); STAGE32_B(0);
  STAGE32_A(1); STAGE32_B(1);
  STAGE32_A(2); STAGE32_B(2);
  WAITV8(); BAR();

  // ---- main: 124 tiles, stage t+3 during t, vmcnt(8) at each tile end
  for (int u = 0; u < 31; ++u) {
    int t3 = 4 * u + 3;
    TILE32(0, 1, t3,     WAITV8());
    TILE32(1, 1, t3 + 1, WAITV8());
    TILE32(2, 1, t3 + 2, WAITV8());
    TILE32(3, 1, t3 + 3, WAITV8());
  }
  // ---- tail: t=124 stages 127; then drain
  TILE32(0, 1, 127, WAITV8());
  TILE32(1, 0, 0, WAITV4());
  TILE32(2, 0, 0, WAITV0());
  TILE32(3, 0, 0, );

  // ---- epilogue: D layout col=lane&15, row=(lane>>4)*4+q
#pragma unroll
  for (int mi = 0; mi < 8; ++mi)
#pragma unroll
    for (int ni = 0; ni < 4; ++ni)
#pragma unroll
      for (int q = 0; q < 4; ++q) {
        int m = m0 + wr * 128 + mi * 16 + j4 * 4 + q;
        int n = n0 + wc * 64 + ni * 16 + l15;
        out[(size_t)m * IN_DIM + n] = acc[mi][ni][q];
      }
#undef TILE32
#undef MM01
#undef MM23
#undef RD_A
#undef RD_B01
#undef RD_B23
#undef STAGE32_A
#undef STAGE32_B
}

// ---------------- fallback (direct f32 path, from round 1) ----------------
#define MT 256
#define NTHR 512
#define NWG ((M_TOT / MT) * R_BLK)

__launch_bounds__(NTHR, 4)
__global__ void bsmm_f32(const float* __restrict__ x32, const float* __restrict__ v32,
                         const int* __restrict__ cols, float* __restrict__ out) {
  __shared__ ushort lx[MT * 64];
  __shared__ ushort lv[16 * 64];
  __shared__ int lcol[K_CNT];
  int b = blockIdx.x;
  int logical = (b & 7) * (NWG >> 3) + (b >> 3);
  int mt = logical >> 8;
  int r  = logical & 255;
  int m0 = mt * MT;
  int tid = threadIdx.x;
  if (tid < K_CNT) lcol[tid] = cols[r * K_CNT + tid];
  int lane = tid & 63, wave = tid >> 6;
  int l15 = lane & 15, j4 = lane >> 4;
  f32x4 acc0 = {0.f, 0.f, 0.f, 0.f};
  f32x4 acc1 = {0.f, 0.f, 0.f, 0.f};
  for (int t = 0; t < K_CNT / 4; ++t) {
    __syncthreads();
#pragma unroll
    for (int s = 0; s < 4; ++s) {
      int ch = s * NTHR + tid;
      int row = ch >> 3, s8 = ch & 7;
      int cb = lcol[t * 4 + (s8 >> 1)];
      size_t goff = (size_t)(m0 + row) * IN_DIM + cb * 16 + (s8 & 1) * 8;
      const f32x4* p = (const f32x4*)(x32 + goff);
      f32x4 a = p[0], bq = p[1];
      bf16x8 val;
      val[0] = f2bf(a[0]);  val[1] = f2bf(a[1]);  val[2] = f2bf(a[2]);  val[3] = f2bf(a[3]);
      val[4] = f2bf(bq[0]); val[5] = f2bf(bq[1]); val[6] = f2bf(bq[2]); val[7] = f2bf(bq[3]);
      int byteo = row * 128 + ((s8 * 16) ^ ((row & 7) << 4));
      *(bf16x8*)((char*)lx + byteo) = val;
    }
    if (tid < 128) {
      int kb = tid >> 5, o = (tid >> 1) & 15, ih = tid & 1;
      size_t goff = ((size_t)r * K_CNT + t * 4 + kb) * 256 + o * 16 + ih * 8;
      const f32x4* p = (const f32x4*)(v32 + goff);
      f32x4 a = p[0], bq = p[1];
      bf16x8 val;
      val[0] = f2bf(a[0]);  val[1] = f2bf(a[1]);  val[2] = f2bf(a[2]);  val[3] = f2bf(a[3]);
      val[4] = f2bf(bq[0]); val[5] = f2bf(bq[1]); val[6] = f2bf(bq[2]); val[7] = f2bf(bq[3]);
      int byteo = o * 128 + (((kb * 2 + ih) * 16) ^ ((o & 7) << 4));
      *(bf16x8*)((char*)lv + byteo) = val;
    }
    __syncthreads();
#pragma unroll
    for (int ks = 0; ks < 2; ++ks) {
      int colb = ks * 64 + j4 * 16;
      bf16x8 bfrg = *(const bf16x8*)((char*)lv + l15 * 128 + (colb ^ ((l15 & 7) << 4)));
      int rowA0 = wave * 32 + l15;
      bf16x8 a0 = *(const bf16x8*)((char*)lx + rowA0 * 128 + (colb ^ ((rowA0 & 7) << 4)));
      int rowA1 = rowA0 + 16;
      bf16x8 a1 = *(const bf16x8*)((char*)lx + rowA1 * 128 + (colb ^ ((rowA1 & 7) << 4)));
      acc0 = __builtin_amdgcn_mfma_f32_16x16x32_bf16(a0, bfrg, acc0, 0, 0, 0);
      acc1 = __builtin_amdgcn_mfma_f32_16x16x32_bf16(a1, bfrg, acc1, 0, 0, 0);
    }
  }
#pragma unroll
  for (int q = 0; q < 4; ++q) {
    int row0 = m0 + wave * 32 + j4 * 4 + q;
    out[(size_t)row0 * 4096 + r * 16 + l15] = acc0[q];
    out[(size_t)(row0 + 16) * 4096 + r * 16 + l15] = acc1[q];
  }
}

extern "C" void kernel_launch(void* const* d_in, const int* in_sizes, int n_in,
                              void* d_out, int out_size, void* d_ws, size_t ws_size,
                              hipStream_t stream) {
  const float* x32 = (const float*)d_in[0];
  const float* v32 = (const float*)d_in[1];
  const int*   cols = (const int*)d_in[2];
  float* out = (float*)d_out;

  const size_t xel = (size_t)M_TOT * IN_DIM;   // 33.5M
  const size_t wel = (size_t)IN_DIM * IN_DIM;  // 16.8M
  const size_t need = xel * 2 + wel * 2;       // xbf + Wbf = 100.7 MB

  if (ws_size >= need) {
    __bf16* xbf = (__bf16*)d_ws;
    __bf16* Wbf = (__bf16*)((char*)d_ws + xel * 2);
    cvt_f32_bf16<<<(int)(xel / 8 / 256), 256, 0, stream>>>(x32, xbf, (int)(xel / 8));
    wbuild2<<<R_BLK * 8, 256, 0, stream>>>(v32, cols, Wbf);
    (void)hipFuncSetAttribute((const void*)gemm32,
                              hipFuncAttributeMaxDynamicSharedMemorySize, 131072);
    gemm32<<<512, 512, 131072, stream>>>(xbf, Wbf, out);
  } else {
    bsmm_f32<<<NWG, NTHR, 0, stream>>>(x32, v32, cols, out);
  }
}